// Round 12
// baseline (7434.634 us; speedup 1.0000x reference)
//
#include <hip/hip_runtime.h>
#include <math.h>

using ushort_t = unsigned short;
using short8 = __attribute__((ext_vector_type(8))) short;
using floatx16 = __attribute__((ext_vector_type(16))) float;
using int4v = __attribute__((ext_vector_type(4))) int;
using int2v = __attribute__((ext_vector_type(2))) int;

constexpr int kB = 512, kT = 256, kH = 512, kHor = 64;
constexpr int NG = 4 * kH;  // 2048 packed gate rows

__device__ __forceinline__ ushort_t f2bf(float v) {
  unsigned u = __builtin_bit_cast(unsigned, v);
  return (ushort_t)((u + 0x7FFFu + ((u >> 16) & 1u)) >> 16);
}
__device__ __forceinline__ float bf2f(ushort_t b) {
  unsigned u = (unsigned)b << 16;
  return __builtin_bit_cast(float, u);
}
__device__ __forceinline__ float sig_(float x) { return 1.0f / (1.0f + __expf(-x)); }

__device__ __forceinline__ void async16(const ushort_t* g, ushort_t* l) {
  __builtin_amdgcn_global_load_lds(
      (const __attribute__((address_space(1))) void*)g,
      (__attribute__((address_space(3))) void*)l, 16, 0, 0);
}

struct UnitP {
  const ushort_t *Whi, *Wlo;            // packed weights [r=j*4+g][k], stride Kw
  const ushort_t *B0hi, *B0lo;          // h source planes (B,H), k 0..511
  const ushort_t *B1hi, *B1lo;          // k 512..1023 (unit B)
  const float* bias;                    // packed [j*4+g]
  ushort_t *Hhi, *Hlo;                  // output h planes (B,H)
  int Kw;                               // 512 or 1024
};

struct EX {
  const float* xsrc; const float* wx; int xmode; int tcol;  // unit-A input term
  float* outp; int ocol;                // ocol>=0: out[:,ocol] = xsrc (LLC)
  float* inp_next; const float* headb; int do_init;
  const float* headW; float* head_acc; int do_head;
};

struct Ptrs {
  const float* x;
  const ushort_t *w0eh, *w0el, *w1eh, *w1el;
  const ushort_t *w0dh, *w0dl, *w1dh, *w1dl;
  ushort_t *h0h[2], *h0l[2], *h1h[2], *h1l[2];
  const float *be0, *be1, *bd0, *bd1, *wxe, *wxd;
  float *ib0, *ib1;
  const float *hW, *hb;
  float* out;
  unsigned *bar1, *barR, *barG;
};

// One GEMM phase: 64 gate-rows x 64 batch, 4 waves of one 32x32 mfma tile.
// (r8 champion kernel; coherence strategy changed:)
//  - h LOADS are PLAIN CACHED. Within an XCD, 8 mb-blocks read the same h
//    panel; L2 now absorbs that 12 MB/XCD/phase redundancy (1 MB unique from
//    LLC). r11 proved the sc read stream (96 MB/phase @ LLC) was the wall.
//  - Freshness: every block's tid0 executes an agent ACQUIRE fence (L1+L2
//    invalidate) after the grid-barrier spin, before any h read. L2 holds
//    no dirty lines EVER (h stores are sc write-through; out/ib stores are
//    agent atomics), so the invalidate is a clean tag-clear and NO release
//    fence is needed (round-1's catastrophe was 512 wbL2 walks over dirty
//    plain stores -- that path no longer exists).
//  - h STORES stay sc0 sc1 (write-through to LLC, drained by vmcnt before
//    barrier arrival) -- identical publish path to r2..r11.
// Weights re-import ~3 MB/XCD/phase from LLC after each invalidate (the
// price); replaces ~12 MB/XCD/phase of sc MALL streaming (the win).
__device__ __forceinline__ void run_unit(const UnitP& U, const EX& E, const bool isB,
                                         const int mb, const int nb,
                                         ushort_t* sm, ushort_t* hshi, ushort_t* hslo,
                                         float* creg) {
  const int tid = threadIdx.x;
  const int m0blk = mb * 64;
  const int n0blk = nb * 64;
  const int nkt = U.Kw >> 6;

  const int wv = tid >> 6;
  const int ln = tid & 63;
  const int l31 = ln & 31;
  const int half = ln >> 5;
  const int wm = wv & 1, wn = wv >> 1;
  const int m0w = wm * 32, n0w = wn * 32;

  // staging invariants (wave 0/1: weight planes hi/lo via DMA;
  //                     wave 2/3: h planes hi/lo via cached reg staging)
  const int r8 = ln >> 3;
  const int k8s = (ln & 7) ^ r8;
  const bool stA = wv < 2;
  const ushort_t* gsrcA = (wv == 0) ? U.Whi : U.Wlo;
  const ushort_t* b0p = (wv == 2) ? U.B0hi : U.B0lo;
  const ushort_t* b1p = (wv == 2) ? U.B1hi : U.B1lo;
  ushort_t* lwb = &sm[wv * 4096];

  int4v breg[8];

  auto issueW = [&](int kt, int bufsel) {
    ushort_t* lb = lwb + bufsel * 16384;
    const ushort_t* g0 = gsrcA + (size_t)(m0blk + r8) * U.Kw + kt * 64 + k8s * 8;
    #pragma unroll
    for (int i = 0; i < 8; ++i)
      async16(g0 + (size_t)i * 8 * U.Kw, lb + i * 512);
  };
  auto issueB = [&](int kt) {
    const ushort_t* bsrc = (kt < 8) ? b0p : b1p;
    const int col0 = (kt & 7) * 64;
    const ushort_t* g0 = bsrc + (size_t)(n0blk + r8) * kH + col0 + k8s * 8;
    #pragma unroll
    for (int i = 0; i < 8; ++i)
      asm volatile("global_load_dwordx4 %0, %1, off"
                   : "=v"(breg[i])
                   : "v"(g0 + (size_t)i * 8 * kH)
                   : "memory");
  };
  auto writeB = [&](int bufsel) {
    ushort_t* lb = lwb + bufsel * 16384;
    asm volatile("s_waitcnt vmcnt(0)" ::: "memory");   // breg materialized
    #pragma unroll
    for (int i = 0; i < 8; ++i)
      *(int4v*)(lb + i * 512 + ln * 8) = breg[i];
    asm volatile("s_waitcnt lgkmcnt(0)" ::: "memory"); // breg reusable + visible
  };

  floatx16 acc;
  #pragma unroll
  for (int i = 0; i < 16; ++i) acc[i] = 0.0f;

  if (stA) issueW(0, 0); else issueB(0);

  for (int kt = 0; kt < nkt; ++kt) {
    const int cur = kt & 1;
    if (kt + 1 < nkt) {
      if (kt > 0) {           // WAR: everyone done computing buf[cur^1]
        asm volatile("" ::: "memory");
        __builtin_amdgcn_s_barrier();
        asm volatile("" ::: "memory");
      }
      if (stA) {
        issueW(kt + 1, cur ^ 1);
        asm volatile("" ::: "memory");
        __builtin_amdgcn_s_waitcnt(0xF78);  // vmcnt(8): my cur-tile DMA done
      } else {
        writeB(cur);          // land kt's h data into buf[cur]
        issueB(kt + 1);       // prefetch next tile (L2/LLC)
      }
    } else {
      if (stA) {
        asm volatile("" ::: "memory");
        __builtin_amdgcn_s_waitcnt(0xF70);  // vmcnt(0)
      } else {
        writeB(cur);
      }
    }
    asm volatile("" ::: "memory");
    __builtin_amdgcn_s_barrier();          // all waves' cur data visible
    asm volatile("" ::: "memory");

    const ushort_t* base = &sm[cur * 16384];
    #pragma unroll
    for (int ks = 0; ks < 4; ++ks) {
      const int k8 = ks * 2 + half;
      const int qa = (m0w + l31) * 8 + (k8 ^ (l31 & 7));
      const int qb = (n0w + l31) * 8 + (k8 ^ (l31 & 7));
      short8 ahi = *(const short8*)(base + qa * 8);
      short8 alo = *(const short8*)(base + 4096 + qa * 8);
      short8 bhi = *(const short8*)(base + 8192 + qb * 8);
      short8 blo = *(const short8*)(base + 12288 + qb * 8);
      acc = __builtin_amdgcn_mfma_f32_32x32x16_bf16(alo, bhi, acc, 0, 0, 0);
      acc = __builtin_amdgcn_mfma_f32_32x32x16_bf16(ahi, blo, acc, 0, 0, 0);
      acc = __builtin_amdgcn_mfma_f32_32x32x16_bf16(ahi, bhi, acc, 0, 0, 0);
    }
  }

  // ---- epilogue: lane holds 4 j-groups x 4 gates for one n ----
  const int jt0 = mb * 16;
  const int ng = n0blk + n0w + l31;
  float xv = 0.0f;
  if (!isB) {
    if (E.xmode == 0) xv = E.xsrc[(size_t)ng * kT + E.tcol];
    else xv = __hip_atomic_load((float*)&E.xsrc[ng], __ATOMIC_RELAXED,
                                __HIP_MEMORY_SCOPE_AGENT);
  }

  #pragma unroll
  for (int rg = 0; rg < 4; ++rg) {
    const int jl = wm * 8 + rg * 2 + half;      // j within block's 16
    const int jg = jt0 + jl;
    const float4 bi = *(const float4*)&U.bias[jg * 4];
    float gi = acc[rg * 4 + 0] + bi.x;
    float gf = acc[rg * 4 + 1] + bi.y;
    float gg = acc[rg * 4 + 2] + bi.z;
    float go = acc[rg * 4 + 3] + bi.w;
    if (!isB) {
      const float4 wx4 = *(const float4*)&E.wx[jg * 4];
      gi += xv * wx4.x; gf += xv * wx4.y; gg += xv * wx4.z; go += xv * wx4.w;
    }
    const float i_ = sig_(gi), f_ = sig_(gf), g_ = tanhf(gg), o_ = sig_(go);
    const float cn = f_ * creg[rg] + i_ * g_;   // c lives in registers
    creg[rg] = cn;
    const float hn = o_ * tanhf(cn);
    const ushort_t hhi = f2bf(hn);
    const ushort_t hlo = f2bf(hn - bf2f(hhi));
    const int nbk = n0w + l31;
    hshi[nbk * 18 + jl] = hhi;
    hslo[nbk * 18 + jl] = hlo;
  }
  __syncthreads();

  // coalesced h-plane write (B,H): 4 threads/row x 8B, write-through to LLC
  // (sc0 sc1: no dirty L2 lines ever -> acquire-inv is a clean tag clear)
  {
    const int nbk = tid >> 2;
    const int jq = (tid & 3) * 4;
    const unsigned a0 = hshi[nbk * 18 + jq + 0], a1 = hshi[nbk * 18 + jq + 1];
    const unsigned a2 = hshi[nbk * 18 + jq + 2], a3 = hshi[nbk * 18 + jq + 3];
    const unsigned b0 = hslo[nbk * 18 + jq + 0], b1 = hslo[nbk * 18 + jq + 1];
    const unsigned b2 = hslo[nbk * 18 + jq + 2], b3 = hslo[nbk * 18 + jq + 3];
    int2v vh, vl;
    vh[0] = (int)(a0 | (a1 << 16)); vh[1] = (int)(a2 | (a3 << 16));
    vl[0] = (int)(b0 | (b1 << 16)); vl[1] = (int)(b2 | (b3 << 16));
    ushort_t* ph = &U.Hhi[(size_t)(n0blk + nbk) * kH + jt0 + jq];
    ushort_t* pl = &U.Hlo[(size_t)(n0blk + nbk) * kH + jt0 + jq];
    asm volatile("global_store_dwordx2 %0, %1, off sc0 sc1"
                 :: "v"(ph), "v"(vh) : "memory");
    asm volatile("global_store_dwordx2 %0, %1, off sc0 sc1"
                 :: "v"(pl), "v"(vl) : "memory");
  }

  if (isB) {
    if (E.do_head && tid < 64) {
      float s = 0.0f;
      #pragma unroll
      for (int jb = 0; jb < 16; ++jb)
        s += (bf2f(hshi[tid * 18 + jb]) + bf2f(hslo[tid * 18 + jb])) * E.headW[jt0 + jb];
      atomicAdd(&E.head_acc[n0blk + tid], s);   // device scope -> LLC
    }
  } else if (mb == 0 && tid < 64) {
    const int n = n0blk + tid;
    if (E.do_init)
      __hip_atomic_store(&E.inp_next[n], E.headb[0], __ATOMIC_RELAXED,
                         __HIP_MEMORY_SCOPE_AGENT);
    if (E.ocol >= 0) {
      const float v = __hip_atomic_load((float*)&E.xsrc[n], __ATOMIC_RELAXED,
                                        __HIP_MEMORY_SCOPE_AGENT);
      // agent atomic store: straight to LLC, never a dirty L2 line
      __hip_atomic_store(&E.outp[(size_t)n * kHor + E.ocol], v,
                         __ATOMIC_RELAXED, __HIP_MEMORY_SCOPE_AGENT);
    }
  }
}

// Persistent kernel: 512 blocks (A-team 0..255, B-team 256..511).
// 2-D XCD mapping (r8 champion):
//   x = bid&7 (~XCD under round-robin), kq = bid>>3,
//   mb = (kq&7) + 8*(x&3)  -> 8 mb-slices per XCD (weights L2-resident
//                             between invalidates; LLC-resident always)
//   nb = (kq>>3) + 4*(x>>2) -> 4 nb panels per XCD (minimal h import)
// A-team bid and B-team bid+256 share (mb,nb) AND (round-robin) a CU ->
// their h0 reads share L1/L2.
__global__ __launch_bounds__(256, 2) void lstm_persist(Ptrs P) {
  __shared__ __align__(16) ushort_t sm[32768];   // 2 buffers x 4 planes x 4096
  __shared__ ushort_t hshi[64 * 18];
  __shared__ ushort_t hslo[64 * 18];

  const int tid = threadIdx.x;
  const int bx = blockIdx.x;
  const bool isB = bx >= 256;
  const int bid = isB ? bx - 256 : bx;
  const int xs = bid & 7;            // ~XCD id under round-robin dispatch
  const int kq = bid >> 3;           // 0..31
  const int mb = (kq & 7) + 8 * (xs & 3);
  const int nb = (kq >> 3) + 4 * (xs >> 2);

  float creg[4] = {0.0f, 0.0f, 0.0f, 0.0f};  // block-private cell state

  int gen = 0;
  auto gbar = [&]() {
    asm volatile("s_waitcnt vmcnt(0)" ::: "memory");  // drain sc-stores -> LLC
    __syncthreads();
    if (tid == 0) {
      unsigned old = __hip_atomic_fetch_add(&P.bar1[(bx & 63) * 32], 1u,
                         __ATOMIC_RELAXED, __HIP_MEMORY_SCOPE_AGENT);
      if (old == (unsigned)(gen * 8 + 7)) {                // last of my 8-group
        unsigned o2 = __hip_atomic_fetch_add(P.barR, 1u,
                          __ATOMIC_RELAXED, __HIP_MEMORY_SCOPE_AGENT);
        if (o2 == (unsigned)(gen * 64 + 63))               // last group
          __hip_atomic_store(P.barG, (unsigned)(gen + 1),
                             __ATOMIC_RELAXED, __HIP_MEMORY_SCOPE_AGENT);
      }
      while (__hip_atomic_load(P.barG, __ATOMIC_RELAXED,
                               __HIP_MEMORY_SCOPE_AGENT) <= (unsigned)gen)
        __builtin_amdgcn_s_sleep(2);
      // L1+L2 invalidate: next phase's plain-cached h reads see fresh LLC.
      // L2 holds no dirty lines (all cross-block writes are sc/atomic),
      // so this is a clean tag-clear -- no writeback walk (cf. round 1).
      __builtin_amdgcn_fence(__ATOMIC_ACQUIRE, "agent");
    }
    __syncthreads();
    ++gen;
  };

  // ---------- encoder: wavefront phases p=0..256 (L0[p] || L1[p-1]) ----------
  for (int p = 0; p <= kT; ++p) {
    const int rd = p & 1, wr = (p + 1) & 1;
    const bool active = isB ? (p >= 1) : (p < kT);
    if (active) {
      UnitP U; EX E = {};
      if (!isB) {
        U = UnitP{P.w0eh, P.w0el, P.h0h[rd], P.h0l[rd], P.h0h[rd], P.h0l[rd],
                  P.be0, P.h0h[wr], P.h0l[wr], 512};
        E.xsrc = P.x; E.wx = P.wxe; E.xmode = 0; E.tcol = p; E.ocol = -1;
      } else {
        U = UnitP{P.w1eh, P.w1el, P.h0h[rd], P.h0l[rd], P.h1h[rd], P.h1l[rd],
                  P.be1, P.h1h[wr], P.h1l[wr], 1024};
        E.ocol = -1;
      }
      run_unit(U, E, isB, mb, nb, sm, hshi, hslo, creg);
    }
    gbar();
  }
  // h0 final in planes[0], h1 final in planes[1]

  // ---------- decoder: serial, 2 phases/step ----------
  for (int t = 0; t < kHor; ++t) {
    const int r0 = t & 1, w0i = (t + 1) & 1;
    const int r1 = (t + 1) & 1, w1i = t & 1;
    float* ibr = (t & 1) ? P.ib1 : P.ib0;
    float* ibw = (t & 1) ? P.ib0 : P.ib1;
    if (!isB) {
      UnitP U = {P.w0dh, P.w0dl, P.h0h[r0], P.h0l[r0], P.h0h[r0], P.h0l[r0],
                 P.bd0, P.h0h[w0i], P.h0l[w0i], 512};
      EX E = {};
      E.wx = P.wxd;
      if (t == 0) { E.xsrc = P.x; E.xmode = 0; E.tcol = 255; E.ocol = -1; }
      else        { E.xsrc = ibr; E.xmode = 1; E.ocol = t - 1; E.outp = P.out; }
      E.do_init = 1; E.inp_next = ibw; E.headb = P.hb;
      run_unit(U, E, false, mb, nb, sm, hshi, hslo, creg);
    }
    gbar();
    if (isB) {
      UnitP U = {P.w1dh, P.w1dl, P.h0h[w0i], P.h0l[w0i], P.h1h[r1], P.h1l[r1],
                 P.bd1, P.h1h[w1i], P.h1l[w1i], 1024};
      EX E = {};
      E.ocol = -1;
      E.do_head = 1; E.headW = P.hW; E.head_acc = ibw;
      run_unit(U, E, true, mb, nb, sm, hshi, hslo, creg);
    }
    gbar();
  }

  // last head output: out[:,63] = ib0 (post-barrier, fresh; kernel-end flush)
  if (!isB && mb == 0 && tid < 64) {
    const int n = nb * 64 + tid;
    const float v =
        __hip_atomic_load(P.ib0 + n, __ATOMIC_RELAXED, __HIP_MEMORY_SCOPE_AGENT);
    __hip_atomic_store(&P.out[(size_t)n * kHor + 63], v,
                       __ATOMIC_RELAXED, __HIP_MEMORY_SCOPE_AGENT);
  }
}

// ---- prep kernels ----
__global__ void prep_w(const float* __restrict__ s0, const float* __restrict__ s1,
                       ushort_t* __restrict__ hi, ushort_t* __restrict__ lo, int Kw) {
  const int k = blockIdx.x * 256 + threadIdx.x;
  const int r = blockIdx.y;                 // packed row j*4+g
  const int j = r >> 2, g = r & 3;
  const int srow = g * kH + j;
  const float v = (k < kH) ? s0[(size_t)srow * kH + k]
                           : s1[(size_t)srow * kH + (k - kH)];
  const ushort_t h = f2bf(v);
  const ushort_t l = f2bf(v - bf2f(h));
  hi[(size_t)r * Kw + k] = h;
  lo[(size_t)r * Kw + k] = l;
}

__global__ void prep_vec(const float* __restrict__ src, float* __restrict__ dst) {
  const int t = blockIdx.x * 256 + threadIdx.x;   // 2048
  const int j = t >> 2, g = t & 3;
  dst[t] = src[g * kH + j];
}

__global__ void init_zero(ushort_t* p0, ushort_t* p1, ushort_t* p2, ushort_t* p3,
                          ushort_t* p4, ushort_t* p5, ushort_t* p6, ushort_t* p7) {
  const int i = blockIdx.x * 256 + threadIdx.x;   // 262144
  p0[i] = 0; p1[i] = 0; p2[i] = 0; p3[i] = 0;
  p4[i] = 0; p5[i] = 0; p6[i] = 0; p7[i] = 0;
}

__global__ void init_bar(unsigned* b) {
  const int i = blockIdx.x * 256 + threadIdx.x;
  if (i < 2112) b[i] = 0;
}

extern "C" void kernel_launch(void* const* d_in, const int* in_sizes, int n_in,
                              void* d_out, int out_size, void* d_ws, size_t ws_size,
                              hipStream_t stream) {
  const float* x     = (const float*)d_in[0];
  const float* eWih0 = (const float*)d_in[1];
  const float* eWhh0 = (const float*)d_in[2];
  const float* eb0   = (const float*)d_in[3];
  const float* eWih1 = (const float*)d_in[4];
  const float* eWhh1 = (const float*)d_in[5];
  const float* eb1   = (const float*)d_in[6];
  const float* dWih0 = (const float*)d_in[7];
  const float* dWhh0 = (const float*)d_in[8];
  const float* db0   = (const float*)d_in[9];
  const float* dWih1 = (const float*)d_in[10];
  const float* dWhh1 = (const float*)d_in[11];
  const float* db1   = (const float*)d_in[12];
  const float* hW    = (const float*)d_in[13];
  const float* hb    = (const float*)d_in[14];
  float* out = (float*)d_out;

  char* w = (char*)d_ws;
  size_t off = 0;
  auto aus = [&](size_t n) { ushort_t* p = (ushort_t*)(w + off); off += ((n * 2 + 255) & ~(size_t)255); return p; };
  auto afl = [&](size_t n) { float* p = (float*)(w + off); off += ((n * 4 + 255) & ~(size_t)255); return p; };

  ushort_t* w0e_hi = aus((size_t)NG * 512); ushort_t* w0e_lo = aus((size_t)NG * 512);
  ushort_t* w1e_hi = aus((size_t)NG * 1024); ushort_t* w1e_lo = aus((size_t)NG * 1024);
  ushort_t* w0d_hi = aus((size_t)NG * 512); ushort_t* w0d_lo = aus((size_t)NG * 512);
  ushort_t* w1d_hi = aus((size_t)NG * 1024); ushort_t* w1d_lo = aus((size_t)NG * 1024);
  ushort_t* h0hi[2] = {aus(kB * kH), aus(kB * kH)};
  ushort_t* h0lo[2] = {aus(kB * kH), aus(kB * kH)};
  ushort_t* h1hi[2] = {aus(kB * kH), aus(kB * kH)};
  ushort_t* h1lo[2] = {aus(kB * kH), aus(kB * kH)};
  float* be0 = afl(NG); float* be1 = afl(NG);
  float* bd0 = afl(NG); float* bd1 = afl(NG);
  float* wxe = afl(NG); float* wxd = afl(NG);
  float* ib0 = afl(kB); float* ib1 = afl(kB);
  unsigned* barb = (unsigned*)(w + off); off += ((2112 * 4 + 255) & ~(size_t)255);

  prep_w<<<dim3(2, NG), 256, 0, stream>>>(eWhh0, eWhh0, w0e_hi, w0e_lo, 512);
  prep_w<<<dim3(4, NG), 256, 0, stream>>>(eWih1, eWhh1, w1e_hi, w1e_lo, 1024);
  prep_w<<<dim3(2, NG), 256, 0, stream>>>(dWhh0, dWhh0, w0d_hi, w0d_lo, 512);
  prep_w<<<dim3(4, NG), 256, 0, stream>>>(dWih1, dWhh1, w1d_hi, w1d_lo, 1024);
  prep_vec<<<8, 256, 0, stream>>>(eb0, be0);
  prep_vec<<<8, 256, 0, stream>>>(eb1, be1);
  prep_vec<<<8, 256, 0, stream>>>(db0, bd0);
  prep_vec<<<8, 256, 0, stream>>>(db1, bd1);
  prep_vec<<<8, 256, 0, stream>>>(eWih0, wxe);
  prep_vec<<<8, 256, 0, stream>>>(dWih0, wxd);
  init_zero<<<1024, 256, 0, stream>>>(h0hi[0], h0hi[1], h0lo[0], h0lo[1],
                                      h1hi[0], h1hi[1], h1lo[0], h1lo[1]);
  init_bar<<<9, 256, 0, stream>>>(barb);

  Ptrs P = {};
  P.x = x;
  P.w0eh = w0e_hi; P.w0el = w0e_lo; P.w1eh = w1e_hi; P.w1el = w1e_lo;
  P.w0dh = w0d_hi; P.w0dl = w0d_lo; P.w1dh = w1d_hi; P.w1dl = w1d_lo;
  P.h0h[0] = h0hi[0]; P.h0h[1] = h0hi[1];
  P.h0l[0] = h0lo[0]; P.h0l[1] = h0lo[1];
  P.h1h[0] = h1hi[0]; P.h1h[1] = h1hi[1];
  P.h1l[0] = h1lo[0]; P.h1l[1] = h1lo[1];
  P.be0 = be0; P.be1 = be1; P.bd0 = bd0; P.bd1 = bd1;
  P.wxe = wxe; P.wxd = wxd;
  P.ib0 = ib0; P.ib1 = ib1;
  P.hW = hW; P.hb = hb;
  P.out = out;
  P.bar1 = barb; P.barR = barb + 2048; P.barG = barb + 2080;

  lstm_persist<<<512, 256, 0, stream>>>(P);
}

// Round 14
// 5725.904 us; speedup vs baseline: 1.2984x; 1.2984x over previous
//
#include <hip/hip_runtime.h>
#include <math.h>

using ushort_t = unsigned short;
using short8 = __attribute__((ext_vector_type(8))) short;
using floatx16 = __attribute__((ext_vector_type(16))) float;
using int4v = __attribute__((ext_vector_type(4))) int;
using int2v = __attribute__((ext_vector_type(2))) int;

constexpr int kB = 512, kT = 256, kH = 512, kHor = 64;
constexpr int NG = 4 * kH;  // 2048 packed gate rows

__device__ __forceinline__ ushort_t f2bf(float v) {
  unsigned u = __builtin_bit_cast(unsigned, v);
  return (ushort_t)((u + 0x7FFFu + ((u >> 16) & 1u)) >> 16);
}
__device__ __forceinline__ float bf2f(ushort_t b) {
  unsigned u = (unsigned)b << 16;
  return __builtin_bit_cast(float, u);
}
__device__ __forceinline__ float sig_(float x) { return 1.0f / (1.0f + __expf(-x)); }

__device__ __forceinline__ void async16(const ushort_t* g, ushort_t* l) {
  __builtin_amdgcn_global_load_lds(
      (const __attribute__((address_space(1))) void*)g,
      (__attribute__((address_space(3))) void*)l, 16, 0, 0);
}

struct UnitP {
  const ushort_t *Whi, *Wlo;            // packed weights [r=j*4+g][k], stride Kw
  const ushort_t *B0hi, *B0lo;          // h source planes (B,H), k 0..511
  const ushort_t *B1hi, *B1lo;          // k 512..1023 (unit B)
  const float* bias;                    // packed [j*4+g]
  ushort_t *Hhi, *Hlo;                  // output h planes (B,H)
  int Kw;                               // 512 or 1024
};

struct EX {
  const float* xsrc; const float* wx; int xmode; int tcol;  // unit-A input term
  float* outp; int ocol;                // ocol>=0: out[:,ocol] = xsrc (LLC)
  float* inp_next; const float* headb; int do_init;
  const float* headW; float* head_acc; int do_head;
};

struct Ptrs {
  const float* x;
  const ushort_t *w0eh, *w0el, *w1eh, *w1el;
  const ushort_t *w0dh, *w0dl, *w1dh, *w1dl;
  ushort_t *h0h[2], *h0l[2], *h1h[2], *h1l[2];
  const float *be0, *be1, *bd0, *bd1, *wxe, *wxd;
  float *ib0, *ib1;
  const float *hW, *hb;
  float* out;
  unsigned *bar1, *barR, *barG;
};

// One GEMM phase: 64 gate-rows x 64 batch, 4 waves of one 32x32 mfma tile.
// (r8 champion kernel, byte-identical compute/staging/numerics.)
// Weights: plain cached global_load_lds DMA -> L2-resident (never fenced).
// h planes: sc0 sc1 write-through stores + sc0 sc1 reads, coherent at LLC.
__device__ __forceinline__ void run_unit(const UnitP& U, const EX& E, const bool isB,
                                         const int mb, const int nb,
                                         ushort_t* sm, ushort_t* hshi, ushort_t* hslo,
                                         float* creg) {
  const int tid = threadIdx.x;
  const int m0blk = mb * 64;
  const int n0blk = nb * 64;
  const int nkt = U.Kw >> 6;

  const int wv = tid >> 6;
  const int ln = tid & 63;
  const int l31 = ln & 31;
  const int half = ln >> 5;
  const int wm = wv & 1, wn = wv >> 1;
  const int m0w = wm * 32, n0w = wn * 32;

  // staging invariants (wave 0/1: weight planes hi/lo via DMA;
  //                     wave 2/3: h planes hi/lo via sc-coherent reg staging)
  const int r8 = ln >> 3;
  const int k8s = (ln & 7) ^ r8;
  const bool stA = wv < 2;
  const ushort_t* gsrcA = (wv == 0) ? U.Whi : U.Wlo;
  const ushort_t* b0p = (wv == 2) ? U.B0hi : U.B0lo;
  const ushort_t* b1p = (wv == 2) ? U.B1hi : U.B1lo;
  ushort_t* lwb = &sm[wv * 4096];

  int4v breg[8];

  auto issueW = [&](int kt, int bufsel) {
    ushort_t* lb = lwb + bufsel * 16384;
    const ushort_t* g0 = gsrcA + (size_t)(m0blk + r8) * U.Kw + kt * 64 + k8s * 8;
    #pragma unroll
    for (int i = 0; i < 8; ++i)
      async16(g0 + (size_t)i * 8 * U.Kw, lb + i * 512);
  };
  auto issueB = [&](int kt) {
    const ushort_t* bsrc = (kt < 8) ? b0p : b1p;
    const int col0 = (kt & 7) * 64;
    const ushort_t* g0 = bsrc + (size_t)(n0blk + r8) * kH + col0 + k8s * 8;
    #pragma unroll
    for (int i = 0; i < 8; ++i)
      asm volatile("global_load_dwordx4 %0, %1, off sc0 sc1"
                   : "=v"(breg[i])
                   : "v"(g0 + (size_t)i * 8 * kH)
                   : "memory");
  };
  auto writeB = [&](int bufsel) {
    ushort_t* lb = lwb + bufsel * 16384;
    asm volatile("s_waitcnt vmcnt(0)" ::: "memory");   // breg materialized
    #pragma unroll
    for (int i = 0; i < 8; ++i)
      *(int4v*)(lb + i * 512 + ln * 8) = breg[i];
    asm volatile("s_waitcnt lgkmcnt(0)" ::: "memory"); // breg reusable + visible
  };

  floatx16 acc;
  #pragma unroll
  for (int i = 0; i < 16; ++i) acc[i] = 0.0f;

  if (stA) issueW(0, 0); else issueB(0);

  for (int kt = 0; kt < nkt; ++kt) {
    const int cur = kt & 1;
    if (kt + 1 < nkt) {
      if (kt > 0) {           // WAR: everyone done computing buf[cur^1]
        asm volatile("" ::: "memory");
        __builtin_amdgcn_s_barrier();
        asm volatile("" ::: "memory");
      }
      if (stA) {
        issueW(kt + 1, cur ^ 1);
        asm volatile("" ::: "memory");
        __builtin_amdgcn_s_waitcnt(0xF78);  // vmcnt(8): my cur-tile DMA done
      } else {
        writeB(cur);          // land kt's h data into buf[cur]
        issueB(kt + 1);       // prefetch next tile from LLC
      }
    } else {
      if (stA) {
        asm volatile("" ::: "memory");
        __builtin_amdgcn_s_waitcnt(0xF70);  // vmcnt(0)
      } else {
        writeB(cur);
      }
    }
    asm volatile("" ::: "memory");
    __builtin_amdgcn_s_barrier();          // all waves' cur data visible
    asm volatile("" ::: "memory");

    const ushort_t* base = &sm[cur * 16384];
    #pragma unroll
    for (int ks = 0; ks < 4; ++ks) {
      const int k8 = ks * 2 + half;
      const int qa = (m0w + l31) * 8 + (k8 ^ (l31 & 7));
      const int qb = (n0w + l31) * 8 + (k8 ^ (l31 & 7));
      short8 ahi = *(const short8*)(base + qa * 8);
      short8 alo = *(const short8*)(base + 4096 + qa * 8);
      short8 bhi = *(const short8*)(base + 8192 + qb * 8);
      short8 blo = *(const short8*)(base + 12288 + qb * 8);
      acc = __builtin_amdgcn_mfma_f32_32x32x16_bf16(alo, bhi, acc, 0, 0, 0);
      acc = __builtin_amdgcn_mfma_f32_32x32x16_bf16(ahi, blo, acc, 0, 0, 0);
      acc = __builtin_amdgcn_mfma_f32_32x32x16_bf16(ahi, bhi, acc, 0, 0, 0);
    }
  }

  // ---- epilogue: lane holds 4 j-groups x 4 gates for one n ----
  const int jt0 = mb * 16;
  const int ng = n0blk + n0w + l31;
  float xv = 0.0f;
  if (!isB) {
    if (E.xmode == 0) xv = E.xsrc[(size_t)ng * kT + E.tcol];
    else xv = __hip_atomic_load((float*)&E.xsrc[ng], __ATOMIC_RELAXED,
                                __HIP_MEMORY_SCOPE_AGENT);
  }

  #pragma unroll
  for (int rg = 0; rg < 4; ++rg) {
    const int jl = wm * 8 + rg * 2 + half;      // j within block's 16
    const int jg = jt0 + jl;
    const float4 bi = *(const float4*)&U.bias[jg * 4];
    float gi = acc[rg * 4 + 0] + bi.x;
    float gf = acc[rg * 4 + 1] + bi.y;
    float gg = acc[rg * 4 + 2] + bi.z;
    float go = acc[rg * 4 + 3] + bi.w;
    if (!isB) {
      const float4 wx4 = *(const float4*)&E.wx[jg * 4];
      gi += xv * wx4.x; gf += xv * wx4.y; gg += xv * wx4.z; go += xv * wx4.w;
    }
    const float i_ = sig_(gi), f_ = sig_(gf), g_ = tanhf(gg), o_ = sig_(go);
    const float cn = f_ * creg[rg] + i_ * g_;   // c lives in registers
    creg[rg] = cn;
    const float hn = o_ * tanhf(cn);
    const ushort_t hhi = f2bf(hn);
    const ushort_t hlo = f2bf(hn - bf2f(hhi));
    const int nbk = n0w + l31;
    hshi[nbk * 18 + jl] = hhi;
    hslo[nbk * 18 + jl] = hlo;
  }
  __syncthreads();

  // coalesced h-plane write (B,H): 4 threads/row x 8B, write-through to LLC
  {
    const int nbk = tid >> 2;
    const int jq = (tid & 3) * 4;
    const unsigned a0 = hshi[nbk * 18 + jq + 0], a1 = hshi[nbk * 18 + jq + 1];
    const unsigned a2 = hshi[nbk * 18 + jq + 2], a3 = hshi[nbk * 18 + jq + 3];
    const unsigned b0 = hslo[nbk * 18 + jq + 0], b1 = hslo[nbk * 18 + jq + 1];
    const unsigned b2 = hslo[nbk * 18 + jq + 2], b3 = hslo[nbk * 18 + jq + 3];
    int2v vh, vl;
    vh[0] = (int)(a0 | (a1 << 16)); vh[1] = (int)(a2 | (a3 << 16));
    vl[0] = (int)(b0 | (b1 << 16)); vl[1] = (int)(b2 | (b3 << 16));
    ushort_t* ph = &U.Hhi[(size_t)(n0blk + nbk) * kH + jt0 + jq];
    ushort_t* pl = &U.Hlo[(size_t)(n0blk + nbk) * kH + jt0 + jq];
    asm volatile("global_store_dwordx2 %0, %1, off sc0 sc1"
                 :: "v"(ph), "v"(vh) : "memory");
    asm volatile("global_store_dwordx2 %0, %1, off sc0 sc1"
                 :: "v"(pl), "v"(vl) : "memory");
  }

  if (isB) {
    if (E.do_head && tid < 64) {
      float s = 0.0f;
      #pragma unroll
      for (int jb = 0; jb < 16; ++jb)
        s += (bf2f(hshi[tid * 18 + jb]) + bf2f(hslo[tid * 18 + jb])) * E.headW[jt0 + jb];
      atomicAdd(&E.head_acc[n0blk + tid], s);   // device scope -> LLC
    }
  } else if (mb == 0 && tid < 64) {
    const int n = n0blk + tid;
    if (E.do_init)
      __hip_atomic_store(&E.inp_next[n], E.headb[0], __ATOMIC_RELAXED,
                         __HIP_MEMORY_SCOPE_AGENT);
    if (E.ocol >= 0) {
      const float v = __hip_atomic_load((float*)&E.xsrc[n], __ATOMIC_RELAXED,
                                        __HIP_MEMORY_SCOPE_AGENT);
      E.outp[(size_t)n * kHor + E.ocol] = v;
    }
  }
}

// Persistent kernel: 512 blocks (A-team 0..255, B-team 256..511).
// 2-D XCD mapping (r8 champion):
//   x = bid&7 (~XCD under round-robin), kq = bid>>3,
//   mb = (kq&7) + 8*(x&3)  -> 8 mb-slices per XCD (enc weights 3 MB, resident)
//   nb = (kq>>3) + 4*(x>>2) -> 4 nb panels per XCD (minimal h import)
//
// r13 (resubmitted after infra failure): per-nb-GROUP barriers instead of one
// global barrier. The dependency graph is closed within an nb-group: block
// (mb,nb) reads h rows [nb*64, nb*64+64) only, written exclusively by blocks
// (*, nb) of both teams (h0 by A-team, h1 by B-team); the decoder ib/head
// chain is per-nb-panel too (do_init by A mb==0, head atomicAdd by B (*,nb),
// read back by A (*,nb)). Synchronizing the 64 blocks (32 A + 32 B) sharing
// nb suffices. Groups are fully independent (disjoint memory) -> no deadlock
// possible; smaller barrier latency, straggler isolation, LLC-stream smoothing.
__global__ __launch_bounds__(256, 2) void lstm_persist(Ptrs P) {
  __shared__ __align__(16) ushort_t sm[32768];   // 2 buffers x 4 planes x 4096
  __shared__ ushort_t hshi[64 * 18];
  __shared__ ushort_t hslo[64 * 18];

  const int tid = threadIdx.x;
  const int bx = blockIdx.x;
  const bool isB = bx >= 256;
  const int bid = isB ? bx - 256 : bx;
  const int xs = bid & 7;            // ~XCD id under round-robin dispatch
  const int kq = bid >> 3;           // 0..31
  const int mb = (kq & 7) + 8 * (xs & 3);
  const int nb = (kq >> 3) + 4 * (xs >> 2);
  const int grp = nb;                // barrier group: 64 blocks (32 A + 32 B)

  float creg[4] = {0.0f, 0.0f, 0.0f, 0.0f};  // block-private cell state

  int gen = 0;
  auto gbar = [&]() {
    asm volatile("s_waitcnt vmcnt(0)" ::: "memory");  // drain sc-stores
    __syncthreads();
    if (tid == 0) {
      unsigned old = __hip_atomic_fetch_add(&P.bar1[grp * 32], 1u,
                         __ATOMIC_RELAXED, __HIP_MEMORY_SCOPE_AGENT);
      if (old == (unsigned)(gen * 64 + 63))            // last of the 64
        __hip_atomic_store(&P.barG[grp * 32], (unsigned)(gen + 1),
                           __ATOMIC_RELAXED, __HIP_MEMORY_SCOPE_AGENT);
      while (__hip_atomic_load(&P.barG[grp * 32], __ATOMIC_RELAXED,
                               __HIP_MEMORY_SCOPE_AGENT) <= (unsigned)gen)
        __builtin_amdgcn_s_sleep(2);
    }
    __syncthreads();
    ++gen;
  };

  // ---------- encoder: wavefront phases p=0..256 (L0[p] || L1[p-1]) ----------
  for (int p = 0; p <= kT; ++p) {
    const int rd = p & 1, wr = (p + 1) & 1;
    const bool active = isB ? (p >= 1) : (p < kT);
    if (active) {
      UnitP U; EX E = {};
      if (!isB) {
        U = UnitP{P.w0eh, P.w0el, P.h0h[rd], P.h0l[rd], P.h0h[rd], P.h0l[rd],
                  P.be0, P.h0h[wr], P.h0l[wr], 512};
        E.xsrc = P.x; E.wx = P.wxe; E.xmode = 0; E.tcol = p; E.ocol = -1;
      } else {
        U = UnitP{P.w1eh, P.w1el, P.h0h[rd], P.h0l[rd], P.h1h[rd], P.h1l[rd],
                  P.be1, P.h1h[wr], P.h1l[wr], 1024};
        E.ocol = -1;
      }
      run_unit(U, E, isB, mb, nb, sm, hshi, hslo, creg);
    }
    gbar();
  }
  // h0 final in planes[0], h1 final in planes[1]

  // ---------- decoder: serial, 2 phases/step ----------
  for (int t = 0; t < kHor; ++t) {
    const int r0 = t & 1, w0i = (t + 1) & 1;
    const int r1 = (t + 1) & 1, w1i = t & 1;
    float* ibr = (t & 1) ? P.ib1 : P.ib0;
    float* ibw = (t & 1) ? P.ib0 : P.ib1;
    if (!isB) {
      UnitP U = {P.w0dh, P.w0dl, P.h0h[r0], P.h0l[r0], P.h0h[r0], P.h0l[r0],
                 P.bd0, P.h0h[w0i], P.h0l[w0i], 512};
      EX E = {};
      E.wx = P.wxd;
      if (t == 0) { E.xsrc = P.x; E.xmode = 0; E.tcol = 255; E.ocol = -1; }
      else        { E.xsrc = ibr; E.xmode = 1; E.ocol = t - 1; E.outp = P.out; }
      E.do_init = 1; E.inp_next = ibw; E.headb = P.hb;
      run_unit(U, E, false, mb, nb, sm, hshi, hslo, creg);
    }
    gbar();
    if (isB) {
      UnitP U = {P.w1dh, P.w1dl, P.h0h[w0i], P.h0l[w0i], P.h1h[r1], P.h1l[r1],
                 P.bd1, P.h1h[w1i], P.h1l[w1i], 1024};
      EX E = {};
      E.ocol = -1;
      E.do_head = 1; E.headW = P.hW; E.head_acc = ibw;
      run_unit(U, E, true, mb, nb, sm, hshi, hslo, creg);
    }
    gbar();
  }

  // last head output: out[:,63] = ib[(63+1)&1] = ib0 (post-gbar, group-fresh)
  if (!isB && mb == 0 && tid < 64) {
    const int n = nb * 64 + tid;
    P.out[(size_t)n * kHor + 63] =
        __hip_atomic_load(P.ib0 + n, __ATOMIC_RELAXED, __HIP_MEMORY_SCOPE_AGENT);
  }
}

// ---- prep kernels ----
__global__ void prep_w(const float* __restrict__ s0, const float* __restrict__ s1,
                       ushort_t* __restrict__ hi, ushort_t* __restrict__ lo, int Kw) {
  const int k = blockIdx.x * 256 + threadIdx.x;
  const int r = blockIdx.y;                 // packed row j*4+g
  const int j = r >> 2, g = r & 3;
  const int srow = g * kH + j;
  const float v = (k < kH) ? s0[(size_t)srow * kH + k]
                           : s1[(size_t)srow * kH + (k - kH)];
  const ushort_t h = f2bf(v);
  const ushort_t l = f2bf(v - bf2f(h));
  hi[(size_t)r * Kw + k] = h;
  lo[(size_t)r * Kw + k] = l;
}

__global__ void prep_vec(const float* __restrict__ src, float* __restrict__ dst) {
  const int t = blockIdx.x * 256 + threadIdx.x;   // 2048
  const int j = t >> 2, g = t & 3;
  dst[t] = src[g * kH + j];
}

__global__ void init_zero(ushort_t* p0, ushort_t* p1, ushort_t* p2, ushort_t* p3,
                          ushort_t* p4, ushort_t* p5, ushort_t* p6, ushort_t* p7) {
  const int i = blockIdx.x * 256 + threadIdx.x;   // 262144
  p0[i] = 0; p1[i] = 0; p2[i] = 0; p3[i] = 0;
  p4[i] = 0; p5[i] = 0; p6[i] = 0; p7[i] = 0;
}

__global__ void init_bar(unsigned* b) {
  const int i = blockIdx.x * 256 + threadIdx.x;
  if (i < 2112) b[i] = 0;
}

extern "C" void kernel_launch(void* const* d_in, const int* in_sizes, int n_in,
                              void* d_out, int out_size, void* d_ws, size_t ws_size,
                              hipStream_t stream) {
  const float* x     = (const float*)d_in[0];
  const float* eWih0 = (const float*)d_in[1];
  const float* eWhh0 = (const float*)d_in[2];
  const float* eb0   = (const float*)d_in[3];
  const float* eWih1 = (const float*)d_in[4];
  const float* eWhh1 = (const float*)d_in[5];
  const float* eb1   = (const float*)d_in[6];
  const float* dWih0 = (const float*)d_in[7];
  const float* dWhh0 = (const float*)d_in[8];
  const float* db0   = (const float*)d_in[9];
  const float* dWih1 = (const float*)d_in[10];
  const float* dWhh1 = (const float*)d_in[11];
  const float* db1   = (const float*)d_in[12];
  const float* hW    = (const float*)d_in[13];
  const float* hb    = (const float*)d_in[14];
  float* out = (float*)d_out;

  char* w = (char*)d_ws;
  size_t off = 0;
  auto aus = [&](size_t n) { ushort_t* p = (ushort_t*)(w + off); off += ((n * 2 + 255) & ~(size_t)255); return p; };
  auto afl = [&](size_t n) { float* p = (float*)(w + off); off += ((n * 4 + 255) & ~(size_t)255); return p; };

  ushort_t* w0e_hi = aus((size_t)NG * 512); ushort_t* w0e_lo = aus((size_t)NG * 512);
  ushort_t* w1e_hi = aus((size_t)NG * 1024); ushort_t* w1e_lo = aus((size_t)NG * 1024);
  ushort_t* w0d_hi = aus((size_t)NG * 512); ushort_t* w0d_lo = aus((size_t)NG * 512);
  ushort_t* w1d_hi = aus((size_t)NG * 1024); ushort_t* w1d_lo = aus((size_t)NG * 1024);
  ushort_t* h0hi[2] = {aus(kB * kH), aus(kB * kH)};
  ushort_t* h0lo[2] = {aus(kB * kH), aus(kB * kH)};
  ushort_t* h1hi[2] = {aus(kB * kH), aus(kB * kH)};
  ushort_t* h1lo[2] = {aus(kB * kH), aus(kB * kH)};
  float* be0 = afl(NG); float* be1 = afl(NG);
  float* bd0 = afl(NG); float* bd1 = afl(NG);
  float* wxe = afl(NG); float* wxd = afl(NG);
  float* ib0 = afl(kB); float* ib1 = afl(kB);
  unsigned* barb = (unsigned*)(w + off); off += ((2112 * 4 + 255) & ~(size_t)255);

  prep_w<<<dim3(2, NG), 256, 0, stream>>>(eWhh0, eWhh0, w0e_hi, w0e_lo, 512);
  prep_w<<<dim3(4, NG), 256, 0, stream>>>(eWih1, eWhh1, w1e_hi, w1e_lo, 1024);
  prep_w<<<dim3(2, NG), 256, 0, stream>>>(dWhh0, dWhh0, w0d_hi, w0d_lo, 512);
  prep_w<<<dim3(4, NG), 256, 0, stream>>>(dWih1, dWhh1, w1d_hi, w1d_lo, 1024);
  prep_vec<<<8, 256, 0, stream>>>(eb0, be0);
  prep_vec<<<8, 256, 0, stream>>>(eb1, be1);
  prep_vec<<<8, 256, 0, stream>>>(db0, bd0);
  prep_vec<<<8, 256, 0, stream>>>(db1, bd1);
  prep_vec<<<8, 256, 0, stream>>>(eWih0, wxe);
  prep_vec<<<8, 256, 0, stream>>>(dWih0, wxd);
  init_zero<<<1024, 256, 0, stream>>>(h0hi[0], h0hi[1], h0lo[0], h0lo[1],
                                      h1hi[0], h1hi[1], h1lo[0], h1lo[1]);
  init_bar<<<9, 256, 0, stream>>>(barb);

  Ptrs P = {};
  P.x = x;
  P.w0eh = w0e_hi; P.w0el = w0e_lo; P.w1eh = w1e_hi; P.w1el = w1e_lo;
  P.w0dh = w0d_hi; P.w0dl = w0d_lo; P.w1dh = w1d_hi; P.w1dl = w1d_lo;
  P.h0h[0] = h0hi[0]; P.h0h[1] = h0hi[1];
  P.h0l[0] = h0lo[0]; P.h0l[1] = h0lo[1];
  P.h1h[0] = h1hi[0]; P.h1h[1] = h1hi[1];
  P.h1l[0] = h1lo[0]; P.h1l[1] = h1lo[1];
  P.be0 = be0; P.be1 = be1; P.bd0 = bd0; P.bd1 = bd1;
  P.wxe = wxe; P.wxd = wxd;
  P.ib0 = ib0; P.ib1 = ib1;
  P.hW = hW; P.hb = hb;
  P.out = out;
  P.bar1 = barb; P.barR = barb + 2048; P.barG = barb + 1024;

  lstm_persist<<<512, 256, 0, stream>>>(P);
}